// Round 16
// baseline (566.725 us; speedup 1.0000x reference)
//
#include <hip/hip_runtime.h>
#include <hip/hip_bf16.h>
#include <stdint.h>

// N=50000, E=800000, D=128, H=256, G=64
#define HDIM 256
#define NGRAPH 64
#define NSH 16            // stats shadow copies (atomic contention shard)
#define CSTR 264          // C-stage row stride (shorts)

typedef short s16x8 __attribute__((ext_vector_type(8)));
typedef float f32x4 __attribute__((ext_vector_type(4)));
typedef unsigned int u32x4 __attribute__((ext_vector_type(4)));

union U8 { u32x4 v; unsigned short s[8]; };

__device__ __forceinline__ float bf2f(unsigned short u){
    union { unsigned int i; float f; } x; x.i = ((unsigned int)u) << 16; return x.f;
}
__device__ __forceinline__ unsigned short f2bf(float f){
    union { float f; unsigned int i; } x; x.f = f;
    unsigned int r = x.i + 0x7fffu + ((x.i >> 16) & 1u);
    return (unsigned short)(r >> 16);
}
__device__ __forceinline__ float ldf(const void* p, int i, int f32){
    return f32 ? ((const float*)p)[i] : bf2f(((const unsigned short*)p)[i]);
}

// ---------------- zero workspace + runtime dtype detection ----------------
__global__ void zero_detect_kernel(int* __restrict__ p, int n,
                                   const unsigned short* __restrict__ x,
                                   const int* __restrict__ ei, const int* __restrict__ batch,
                                   int E, int N, int* __restrict__ flags){
    int i = blockIdx.x * 256 + threadIdx.x;
    if (i < n) p[i] = 0;
    if (i == 0){
        int c = 0;
        for (int k = 0; k < 128; k++){
            unsigned e = (x[2 * k] >> 7) & 0xFFu;
            if (e >= 100u && e <= 140u) c++;
        }
        flags[0] = (c < 96) ? 1 : 0;   // x is f32
        int z = (ei[2*E - 1] == 0) && (ei[2*E - 3] == 0) && (ei[2*E - 5] == 0) && (ei[2*E - 7] == 0);
        flags[1] = z ? 1 : 0;          // edge_index is i64
        flags[2] = (batch[N - 1] == 0) ? 1 : 0;  // batch is i64
    }
}

// ---------------- CSR build (4 edges/thread) ----------------
__global__ void hist_kernel(const int* __restrict__ ei, int E, int N,
                            const int* __restrict__ flags, int* __restrict__ deg){
    int is64 = flags[1];
    int base = blockIdx.x * 1024;
    #pragma unroll
    for (int k = 0; k < 4; k++){
        int e = base + k * 256 + threadIdx.x;
        if (e < E){
            int d = is64 ? ei[2 * E + 2 * e] : ei[E + e];
            if ((unsigned)d < (unsigned)N) atomicAdd(&deg[d], 1);
        }
    }
}

__global__ void scan1_kernel(const int* __restrict__ deg, int N,
                             int* __restrict__ incl, int* __restrict__ bsums){
    __shared__ int sm[256];
    int t = threadIdx.x;
    int i = blockIdx.x * 256 + t;
    int v = (i < N) ? deg[i] : 0;
    sm[t] = v; __syncthreads();
    for (int off = 1; off < 256; off <<= 1){
        int tv = (t >= off) ? sm[t - off] : 0;
        __syncthreads();
        sm[t] += tv;
        __syncthreads();
    }
    if (i < N) incl[i] = sm[t];
    if (t == 255) bsums[blockIdx.x] = sm[255];
}

__global__ void scan23_kernel(const int* __restrict__ deg, int N, int E, int nb,
                              const int* __restrict__ bsums, int* __restrict__ rowptr){
    __shared__ int sm[256];
    int t = threadIdx.x;
    int bid = blockIdx.x;
    sm[t] = (t < nb && t < bid) ? bsums[t] : 0;
    __syncthreads();
    for (int s = 128; s > 0; s >>= 1){
        if (t < s) sm[t] += sm[t + s];
        __syncthreads();
    }
    int prefix = sm[0];
    int i = bid * 256 + t;
    if (i < N) rowptr[i] = rowptr[i] - deg[i] + prefix;
    if (i == 0) rowptr[N] = E;
}

__global__ void fill_kernel(const int* __restrict__ ei, int E, int N,
                            const int* __restrict__ flags,
                            const int* __restrict__ rowptr, int* __restrict__ fillc,
                            int* __restrict__ csr){
    int is64 = flags[1];
    int base = blockIdx.x * 1024;
    #pragma unroll
    for (int k = 0; k < 4; k++){
        int e = base + k * 256 + threadIdx.x;
        if (e < E){
            int d = is64 ? ei[2 * E + 2 * e] : ei[E + e];
            int s = is64 ? ei[2 * e]         : ei[e];
            if ((unsigned)d < (unsigned)N){
                int p = atomicAdd(&fillc[d], 1);
                csr[rowptr[d] + p] = s;
            }
        }
    }
}

// ---------------- prep: weights -> bf16 packed chunk-major [kc][n][32], + x conversion ----------------
__global__ void prep_kernel(const void* __restrict__ W1, unsigned short* __restrict__ Wp1,
                            const void* __restrict__ W2, unsigned short* __restrict__ Wp2,
                            const void* __restrict__ W3, unsigned short* __restrict__ Wp3,
                            const void* __restrict__ x, unsigned short* __restrict__ Xc,
                            int nx8, const int* __restrict__ flags){
    int bid = blockIdx.x;
    int f32 = flags[0];
    if (bid < 640){
        const void* W; unsigned short* Wp; int base;
        if (bid < 128)      { W = W1; Wp = Wp1; base = bid; }
        else if (bid < 384) { W = W2; Wp = Wp2; base = bid - 128; }
        else                { W = W3; Wp = Wp3; base = bid - 384; }
        int idx = base * 256 + threadIdx.x;
        int k2 = idx & 31;
        int nn = (idx >> 5) & 255;
        int kc = idx >> 13;
        Wp[idx] = f2bf(ldf(W, (kc * 32 + k2) * 256 + nn, f32));
    } else {
        int i = (bid - 640) * 256 + threadIdx.x;
        if (i >= nx8) return;
        int base = i * 8;
        unsigned short o[8];
        if (f32){
            const float* s = (const float*)x + base;
            float4 a = *(const float4*)s;
            float4 b = *(const float4*)(s + 4);
            o[0]=f2bf(a.x); o[1]=f2bf(a.y); o[2]=f2bf(a.z); o[3]=f2bf(a.w);
            o[4]=f2bf(b.x); o[5]=f2bf(b.y); o[6]=f2bf(b.z); o[7]=f2bf(b.w);
        } else {
            *(uint4*)o = *(const uint4*)((const unsigned short*)x + base);
        }
        *(uint4*)&Xc[base] = *(uint4*)o;
    }
}

// ---------------- plain vectorized aggregation ----------------
template<int C>
__global__ __launch_bounds__(256) void agg_vec(const unsigned short* __restrict__ feat, int ldi,
                                               const int* __restrict__ rowptr, const int* __restrict__ csr,
                                               unsigned short* __restrict__ Y, int ldo, int N){
    constexpr int L   = C / 8;
    constexpr int NPB = 256 / L;
    int node = blockIdx.x * NPB + threadIdx.x / L;
    int lane = threadIdx.x & (L - 1);
    if (node >= N) return;
    int c0 = lane * 8;
    const unsigned short* base = feat + c0;

    U8 t0; t0.v = *(const u32x4*)&feat[(size_t)node * ldi + c0];
    float acc[8];
    #pragma unroll
    for (int j = 0; j < 8; j++) acc[j] = bf2f(t0.s[j]);

    int lo = rowptr[node], hi = rowptr[node + 1];
    int e = lo;
    for (; e + 3 < hi; e += 4){
        int s0 = csr[e], s1 = csr[e + 1], s2 = csr[e + 2], s3 = csr[e + 3];
        U8 ta, tb, tc, td;
        ta.v = *(const u32x4*)&base[(size_t)s0 * ldi];
        tb.v = *(const u32x4*)&base[(size_t)s1 * ldi];
        tc.v = *(const u32x4*)&base[(size_t)s2 * ldi];
        td.v = *(const u32x4*)&base[(size_t)s3 * ldi];
        #pragma unroll
        for (int j = 0; j < 8; j++)
            acc[j] += (bf2f(ta.s[j]) + bf2f(tb.s[j])) + (bf2f(tc.s[j]) + bf2f(td.s[j]));
    }
    for (; e < hi; e++){
        int s0 = csr[e];
        U8 ta; ta.v = *(const u32x4*)&base[(size_t)s0 * ldi];
        #pragma unroll
        for (int j = 0; j < 8; j++) acc[j] += bf2f(ta.s[j]);
    }
    U8 o;
    #pragma unroll
    for (int j = 0; j < 8; j++) o.s[j] = f2bf(acc[j]);
    *(u32x4*)&Y[(size_t)node * ldo + c0] = o.v;
}

// ---- flat GEMM, 128-row in-place blocks (grid 391), BK=32 packed-B, 2x2 wave grid (acc 4x8). ----
// Two-pass LDS C-staging for coalesced stores; shfl quad-reduce + sharded stats atomics.
// C/D layout col=lane&15, row=(lane>>4)*4+reg [m89].
__global__ __launch_bounds__(256) void gemm_tile(
    unsigned short* __restrict__ AC, int K,
    const unsigned short* __restrict__ Bp, const void* __restrict__ bias,
    int M, const int* __restrict__ flags,
    float* __restrict__ S, float* __restrict__ Q)   // S,Q: NSH shadow copies of 256
{
    __shared__ __align__(16) unsigned short smem[64 * CSTR];  // 33.8 KB (K-loop: As+Bs = 15360 shorts)
    __shared__ float sS[256], sQ[256];
    unsigned short* As = smem;              // 128*40 = 5120 shorts
    unsigned short* Bs = smem + 5120;       // 256*40 = 10240 shorts
    const int tid  = threadIdx.x;
    const int wave = tid >> 6, lane = tid & 63;
    const int quad = lane >> 4, l16 = lane & 15;
    const int m0   = blockIdx.x * 128;
    const int wm   = (wave & 1) * 64;
    const int wn   = (wave >> 1) * 128;
    const bool full = (m0 + 128 <= M);
    const int f32  = flags[0];

    sS[tid] = 0.f; sQ[tid] = 0.f;

    const f32x4 zero4 = {0.f, 0.f, 0.f, 0.f};
    f32x4 acc[4][8];
    #pragma unroll
    for (int i = 0; i < 4; i++)
        #pragma unroll
        for (int j = 0; j < 8; j++) acc[i][j] = zero4;

    const int nchunk = K >> 5;
    for (int kc8 = 0; kc8 < nchunk; kc8++){
        int kc = kc8 * 32;
        // stage A: 128 rows x 32 cols = 512 uint4 (2/thread)
        #pragma unroll
        for (int j = 0; j < 2; j++){
            int c = tid + j * 256;
            int r = c >> 2, cc = (c & 3) * 8;
            int gr = m0 + r;
            uint4 va; va.x = va.y = va.z = va.w = 0u;
            if (full || gr < M) va = *(const uint4*)&AC[(size_t)gr * HDIM + kc + cc];
            *(uint4*)&As[r * 40 + cc] = va;
        }
        // stage B: packed contiguous 16 KB chunk -> stride-40 LDS
        {
            const unsigned short* bc = Bp + (size_t)kc8 * 8192;
            #pragma unroll
            for (int j = 0; j < 4; j++){
                int c = tid + j * 256;
                int n = c >> 2, seg = (c & 3) * 8;
                *(uint4*)&Bs[n * 40 + seg] = *(const uint4*)&bc[c * 8];
            }
        }
        __syncthreads();
        s16x8 af[4];
        #pragma unroll
        for (int mt = 0; mt < 4; mt++)
            af[mt] = *(const s16x8*)&As[(wm + mt * 16 + l16) * 40 + quad * 8];
        #pragma unroll
        for (int nt = 0; nt < 8; nt++){
            s16x8 b = *(const s16x8*)&Bs[(wn + nt * 16 + l16) * 40 + quad * 8];
            #pragma unroll
            for (int mt = 0; mt < 4; mt++)
                acc[mt][nt] = __builtin_amdgcn_mfma_f32_16x16x32_bf16(af[mt], b, acc[mt][nt], 0, 0, 0);
        }
        __syncthreads();
    }
    // epilogue: two 64-row passes; stage C to LDS, coalesced stores; stats via shfl + LDS atomics
    #pragma unroll
    for (int pass = 0; pass < 2; pass++){
        if ((wave & 1) == pass){
            #pragma unroll
            for (int nt = 0; nt < 8; nt++){
                int gc = wn + nt * 16 + l16;
                float bv = ldf(bias, gc, f32);
                float ps = 0.f, pq = 0.f;
                #pragma unroll
                for (int mt = 0; mt < 4; mt++){
                    #pragma unroll
                    for (int r = 0; r < 4; r++){
                        int lr = mt * 16 + quad * 4 + r;     // 0..63 within pass
                        int gr = m0 + pass * 64 + lr;
                        float val = acc[mt][nt][r] + bv;
                        smem[lr * CSTR + gc] = f2bf(val);
                        if (full || gr < M){ ps += val; pq += val * val; }
                    }
                }
                ps += __shfl_xor(ps, 16); ps += __shfl_xor(ps, 32);
                pq += __shfl_xor(pq, 16); pq += __shfl_xor(pq, 32);
                if (quad == 0){ atomicAdd(&sS[gc], ps); atomicAdd(&sQ[gc], pq); }
            }
        }
        __syncthreads();
        #pragma unroll
        for (int j = 0; j < 8; j++){
            int lin = j * 256 + tid;
            int row = lin >> 5, coll = (lin & 31) * 8;
            int gr = m0 + pass * 64 + row;
            if (full || gr < M)
                *(uint4*)&AC[(size_t)gr * HDIM + coll] = *(const uint4*)&smem[row * CSTR + coll];
        }
        __syncthreads();
    }
    int sid = (blockIdx.x & (NSH - 1)) * 256 + tid;
    atomicAdd(&S[sid], sS[tid]);
    atomicAdd(&Q[sid], sQ[tid]);
}

// ---------------- bnrelu: reduce shadow stats, scale/shift, relu (+ residual); 16 elems/thread ----------------
__global__ void bnrelu_kernel(const unsigned short* __restrict__ Hin,
                              const float* __restrict__ S, const float* __restrict__ Q,
                              const void* __restrict__ g, const void* __restrict__ be,
                              float invM, const int* __restrict__ flags,
                              const unsigned short* __restrict__ res,
                              unsigned short* __restrict__ Out, int total16){
    __shared__ float sscale[256], sshift[256];
    int tid = threadIdx.x;
    {
        int f32 = flags[0];
        float s = 0.f, q = 0.f;
        #pragma unroll
        for (int k = 0; k < NSH; k++){ s += S[k * 256 + tid]; q += Q[k * 256 + tid]; }
        float m  = s * invM;
        float v  = q * invM - m * m;
        float sc = ldf(g, tid, f32) * rsqrtf(v + 1e-5f);
        sscale[tid] = sc;
        sshift[tid] = ldf(be, tid, f32) - m * sc;
    }
    __syncthreads();
    int idx = blockIdx.x * 256 + tid;
    if (idx >= total16) return;
    #pragma unroll
    for (int h = 0; h < 2; h++){
        int base = idx * 16 + h * 8;
        int c = base & (HDIM - 1);
        unsigned short hv[8], rv[8], ov[8];
        *(uint4*)hv = *(const uint4*)&Hin[base];
        if (res) *(uint4*)rv = *(const uint4*)&res[base];
        #pragma unroll
        for (int j = 0; j < 8; j++){
            float v = bf2f(hv[j]) * sscale[c + j] + sshift[c + j];
            v = (v < 0.f) ? 0.f : v;
            if (res) v += bf2f(rv[j]);
            ov[j] = f2bf(v);
        }
        *(uint4*)&Out[base] = *(uint4*)ov;
    }
}

// ---- layer-3 bnrelu + pool: 64-row strips, 8 walkers x 32 col-groups, uint4 loads. ----
__global__ __launch_bounds__(256) void bnrelu_pool_kernel(
    const unsigned short* __restrict__ H, const unsigned short* __restrict__ res,
    const float* __restrict__ S, const float* __restrict__ Q,
    const void* __restrict__ g, const void* __restrict__ be,
    float invM, const int* __restrict__ flags,
    const int* __restrict__ batch, int N, float* __restrict__ sums)
{
    __shared__ float lsc[256], lsh[256];
    __shared__ float red[8 * 256];
    int tid = threadIdx.x;
    {
        int f32 = flags[0];
        float s = 0.f, q = 0.f;
        #pragma unroll
        for (int k = 0; k < NSH; k++){ s += S[k * 256 + tid]; q += Q[k * 256 + tid]; }
        float m  = s * invM;
        float v  = q * invM - m * m;
        float sc = ldf(g, tid, f32) * rsqrtf(v + 1e-5f);
        lsc[tid] = sc;
        lsh[tid] = ldf(be, tid, f32) - m * sc;
    }
    __syncthreads();
    int r0 = blockIdx.x * 64;
    if (r0 >= N) return;
    int r1 = min(r0 + 64, N);
    int stride = flags[2] ? 2 : 1;
    int gfirst = batch[r0 * stride];
    int glast  = batch[(r1 - 1) * stride];
    int w  = tid >> 5;
    int c0 = (tid & 31) * 8;
    float sc[8], sh[8];
    #pragma unroll
    for (int j = 0; j < 8; j++){ sc[j] = lsc[c0 + j]; sh[j] = lsh[c0 + j]; }

    float acc[8];
    #pragma unroll
    for (int j = 0; j < 8; j++) acc[j] = 0.f;

    if (gfirst == glast){
        for (int r = r0 + w; r < r1; r += 8){
            U8 hv, rv;
            hv.v = *(const u32x4*)&H[(size_t)r * HDIM + c0];
            rv.v = *(const u32x4*)&res[(size_t)r * HDIM + c0];
            #pragma unroll
            for (int j = 0; j < 8; j++){
                float v = bf2f(hv.s[j]) * sc[j] + sh[j];
                v = (v < 0.f) ? 0.f : v;
                acc[j] += v + bf2f(rv.s[j]);
            }
        }
        *(float4*)&red[w * 256 + c0]     = make_float4(acc[0], acc[1], acc[2], acc[3]);
        *(float4*)&red[w * 256 + c0 + 4] = make_float4(acc[4], acc[5], acc[6], acc[7]);
        __syncthreads();
        float tot = 0.f;
        #pragma unroll
        for (int k = 0; k < 8; k++) tot += red[k * 256 + tid];
        atomicAdd(&sums[gfirst * HDIM + tid], tot);
    } else {
        int curg = batch[min(r0 + w, r1 - 1) * stride];
        for (int r = r0 + w; r < r1; r += 8){
            int gg = batch[r * stride];
            if (gg != curg){
                #pragma unroll
                for (int j = 0; j < 8; j++){
                    if (acc[j] != 0.f) atomicAdd(&sums[curg * HDIM + c0 + j], acc[j]);
                    acc[j] = 0.f;
                }
                curg = gg;
            }
            U8 hv, rv;
            hv.v = *(const u32x4*)&H[(size_t)r * HDIM + c0];
            rv.v = *(const u32x4*)&res[(size_t)r * HDIM + c0];
            #pragma unroll
            for (int j = 0; j < 8; j++){
                float v = bf2f(hv.s[j]) * sc[j] + sh[j];
                v = (v < 0.f) ? 0.f : v;
                acc[j] += v + bf2f(rv.s[j]);
            }
        }
        #pragma unroll
        for (int j = 0; j < 8; j++)
            if (acc[j] != 0.f) atomicAdd(&sums[curg * HDIM + c0 + j], acc[j]);
    }
}

// ---------------- FC head (fused pool finalize) ----------------
__global__ __launch_bounds__(256) void head_kernel(const float* __restrict__ sums,
                                                   const int* __restrict__ batch, int N,
                                                   const void* __restrict__ fcW1,
                                                   const void* __restrict__ fcb1,
                                                   const void* __restrict__ fcW2,
                                                   const void* __restrict__ fcb2,
                                                   void* __restrict__ out,
                                                   const int* __restrict__ flags){
    __shared__ float sp[256];
    __shared__ float red[256];
    __shared__ int scnt;
    int g = blockIdx.x, j = threadIdx.x;
    int f32 = flags[0];
    int stride = flags[2] ? 2 : 1;
    if (j == 0){
        int lo = 0, hi = N;
        while (lo < hi){ int mid = (lo + hi) >> 1; if (batch[mid * stride] < g) lo = mid + 1; else hi = mid; }
        int a = lo;
        lo = 0; hi = N;
        while (lo < hi){ int mid = (lo + hi) >> 1; if (batch[mid * stride] < g + 1) lo = mid + 1; else hi = mid; }
        scnt = lo - a;
    }
    __syncthreads();
    sp[j] = sums[g * HDIM + j] / (float)max(scnt, 1);
    __syncthreads();
    float acc = ldf(fcb1, j, f32);
    for (int k = 0; k < HDIM; k++) acc += sp[k] * ldf(fcW1, k * HDIM + j, f32);
    acc = (acc < 0.f) ? 0.f : acc;
    red[j] = acc * ldf(fcW2, j, f32);
    __syncthreads();
    for (int s = 128; s > 0; s >>= 1){
        if (j < s) red[j] += red[j + s];
        __syncthreads();
    }
    if (j == 0){
        float r = red[0] + ldf(fcb2, 0, f32);
        if (f32) ((float*)out)[g] = r;
        else     ((unsigned short*)out)[g] = f2bf(r);
    }
}

extern "C" void kernel_launch(void* const* d_in, const int* in_sizes, int n_in,
                              void* d_out, int out_size, void* d_ws, size_t ws_size,
                              hipStream_t stream)
{
    const unsigned short* x    = (const unsigned short*)d_in[0];
    const int*            ei   = (const int*)d_in[1];
    const int*            batch= (const int*)d_in[2];
    const void* W1   = d_in[4];
    const void* b1   = d_in[5];
    const void* W2   = d_in[6];
    const void* b2   = d_in[7];
    const void* W3   = d_in[8];
    const void* b3   = d_in[9];
    const void* g1   = d_in[10];
    const void* be1  = d_in[11];
    const void* g2   = d_in[12];
    const void* be2  = d_in[13];
    const void* g3   = d_in[14];
    const void* be3  = d_in[15];
    const void* fcW1 = d_in[16];
    const void* fcb1 = d_in[17];
    const void* fcW2 = d_in[18];
    const void* fcb2 = d_in[19];

    const int N = in_sizes[0] / 128;   // 50000
    const int E = in_sizes[1] / 2;     // 800000
    const int D = 128;

    // ---- workspace layout ----
    char* p = (char*)d_ws;
    int*   deg     = (int*)p;   p += (size_t)N * 4;
    int*   fillc   = (int*)p;   p += (size_t)N * 4;
    float* stats   = (float*)p; p += 6 * NSH * 256 * 4;
    float* poolsum = (float*)p; p += NGRAPH * HDIM * 4;
    size_t zbytes  = (size_t)(p - (char*)d_ws);
    int*   flags   = (int*)p;   p += 16 * 4;
    int*   bsums   = (int*)p;   p += 256 * 4;
    int*   rowptr  = (int*)p;   p += ((size_t)N + 4) * 4;
    int*   csr     = (int*)p;   p += (size_t)E * 4;
    unsigned short* Wp1 = (unsigned short*)p; p += 256 * 128 * 2;
    unsigned short* Wp2 = (unsigned short*)p; p += 256 * 256 * 2;
    unsigned short* Wp3 = (unsigned short*)p; p += 256 * 256 * 2;
    unsigned short* B1  = (unsigned short*)p; p += (size_t)N * HDIM * 2;
    unsigned short* B2  = (unsigned short*)p; p += (size_t)N * HDIM * 2;
    unsigned short* Xc  = B1;   // Xc dead before B1 born

    float* S0 = stats + 0 * NSH * 256; float* Q0 = stats + 1 * NSH * 256;
    float* S1 = stats + 2 * NSH * 256; float* Q1 = stats + 3 * NSH * 256;
    float* S2 = stats + 4 * NSH * 256; float* Q2 = stats + 5 * NSH * 256;

    const int nbN = (N + 255) / 256;       // 196
    const int nbE4 = (E + 1023) / 1024;    // 782
    const int gM128 = (N + 127) / 128;     // 391
    const int gM64  = (N + 63) / 64;       // 782
    const float invM = 1.0f / (float)N;
    const int total16 = N * HDIM / 16;
    const int zn = (int)(zbytes / 4);
    const int nx8 = N * D / 8;             // 800000

    zero_detect_kernel<<<(zn + 255) / 256, 256, 0, stream>>>((int*)d_ws, zn, x, ei, batch, E, N, flags);

    // CSR build
    hist_kernel<<<nbE4, 256, 0, stream>>>(ei, E, N, flags, deg);
    scan1_kernel<<<nbN, 256, 0, stream>>>(deg, N, rowptr, bsums);
    scan23_kernel<<<nbN, 256, 0, stream>>>(deg, N, E, nbN, bsums, rowptr);
    fill_kernel<<<nbE4, 256, 0, stream>>>(ei, E, N, flags, rowptr, fillc, csr);

    // weights (packed) + x conversion
    prep_kernel<<<640 + (nx8 + 255) / 256, 256, 0, stream>>>(W1, Wp1, W2, Wp2, W3, Wp3, x, Xc, nx8, flags);

    // ---- Layer 1 ----
    agg_vec<128><<<(N + 15) / 16, 256, 0, stream>>>(Xc, D, rowptr, csr, B2, HDIM, N);
    gemm_tile<<<gM128, 256, 0, stream>>>(B2, 128, Wp1, b1, N, flags, S0, Q0);
    bnrelu_kernel<<<(total16 + 255) / 256, 256, 0, stream>>>(
        B2, S0, Q0, g1, be1, invM, flags, (const unsigned short*)nullptr, B1, total16);

    // ---- Layer 2 ----
    agg_vec<256><<<(N + 7) / 8, 256, 0, stream>>>(B1, HDIM, rowptr, csr, B2, HDIM, N);
    gemm_tile<<<gM128, 256, 0, stream>>>(B2, 256, Wp2, b2, N, flags, S1, Q1);
    bnrelu_kernel<<<(total16 + 255) / 256, 256, 0, stream>>>(
        B2, S1, Q1, g2, be2, invM, flags, B1, B1, total16);

    // ---- Layer 3 (bnrelu fused with pooling) ----
    agg_vec<256><<<(N + 7) / 8, 256, 0, stream>>>(B1, HDIM, rowptr, csr, B2, HDIM, N);
    gemm_tile<<<gM128, 256, 0, stream>>>(B2, 256, Wp3, b3, N, flags, S2, Q2);
    bnrelu_pool_kernel<<<gM64, 256, 0, stream>>>(
        B2, B1, S2, Q2, g3, be3, invM, flags, batch, N, poolsum);

    // ---- Head ----
    head_kernel<<<NGRAPH, 256, 0, stream>>>(poolsum, batch, N, fcW1, fcb1, fcW2, fcb2, d_out, flags);

    (void)n_in; (void)out_size; (void)ws_size;
}

// Round 17
// 514.386 us; speedup vs baseline: 1.1017x; 1.1017x over previous
//
#include <hip/hip_runtime.h>
#include <hip/hip_bf16.h>
#include <stdint.h>

// N=50000, E=800000, D=128, H=256, G=64
#define HDIM 256
#define NGRAPH 64
#define NSH 16            // stats shadow copies (atomic contention shard)
#define CSTR 264          // C-stage row stride (shorts)

typedef short s16x8 __attribute__((ext_vector_type(8)));
typedef float f32x4 __attribute__((ext_vector_type(4)));
typedef unsigned int u32x4 __attribute__((ext_vector_type(4)));

union U8 { u32x4 v; unsigned short s[8]; };

__device__ __forceinline__ float bf2f(unsigned short u){
    union { unsigned int i; float f; } x; x.i = ((unsigned int)u) << 16; return x.f;
}
__device__ __forceinline__ unsigned short f2bf(float f){
    union { float f; unsigned int i; } x; x.f = f;
    unsigned int r = x.i + 0x7fffu + ((x.i >> 16) & 1u);
    return (unsigned short)(r >> 16);
}
__device__ __forceinline__ float ldf(const void* p, int i, int f32){
    return f32 ? ((const float*)p)[i] : bf2f(((const unsigned short*)p)[i]);
}

// ---------------- zero workspace + runtime dtype detection ----------------
__global__ void zero_detect_kernel(int* __restrict__ p, int n,
                                   const unsigned short* __restrict__ x,
                                   const int* __restrict__ ei, const int* __restrict__ batch,
                                   int E, int N, int* __restrict__ flags){
    int i = blockIdx.x * 256 + threadIdx.x;
    if (i < n) p[i] = 0;
    if (i == 0){
        int c = 0;
        for (int k = 0; k < 128; k++){
            unsigned e = (x[2 * k] >> 7) & 0xFFu;
            if (e >= 100u && e <= 140u) c++;
        }
        flags[0] = (c < 96) ? 1 : 0;   // x is f32
        int z = (ei[2*E - 1] == 0) && (ei[2*E - 3] == 0) && (ei[2*E - 5] == 0) && (ei[2*E - 7] == 0);
        flags[1] = z ? 1 : 0;          // edge_index is i64
        flags[2] = (batch[N - 1] == 0) ? 1 : 0;  // batch is i64
    }
}

// ---------------- CSR build (4 edges/thread) ----------------
__global__ void hist_kernel(const int* __restrict__ ei, int E, int N,
                            const int* __restrict__ flags, int* __restrict__ deg){
    int is64 = flags[1];
    int base = blockIdx.x * 1024;
    #pragma unroll
    for (int k = 0; k < 4; k++){
        int e = base + k * 256 + threadIdx.x;
        if (e < E){
            int d = is64 ? ei[2 * E + 2 * e] : ei[E + e];
            if ((unsigned)d < (unsigned)N) atomicAdd(&deg[d], 1);
        }
    }
}

__global__ void scan1_kernel(const int* __restrict__ deg, int N,
                             int* __restrict__ incl, int* __restrict__ bsums){
    __shared__ int sm[256];
    int t = threadIdx.x;
    int i = blockIdx.x * 256 + t;
    int v = (i < N) ? deg[i] : 0;
    sm[t] = v; __syncthreads();
    for (int off = 1; off < 256; off <<= 1){
        int tv = (t >= off) ? sm[t - off] : 0;
        __syncthreads();
        sm[t] += tv;
        __syncthreads();
    }
    if (i < N) incl[i] = sm[t];
    if (t == 255) bsums[blockIdx.x] = sm[255];
}

__global__ void scan23_kernel(const int* __restrict__ deg, int N, int E, int nb,
                              const int* __restrict__ bsums, int* __restrict__ rowptr){
    __shared__ int sm[256];
    int t = threadIdx.x;
    int bid = blockIdx.x;
    sm[t] = (t < nb && t < bid) ? bsums[t] : 0;
    __syncthreads();
    for (int s = 128; s > 0; s >>= 1){
        if (t < s) sm[t] += sm[t + s];
        __syncthreads();
    }
    int prefix = sm[0];
    int i = bid * 256 + t;
    if (i < N) rowptr[i] = rowptr[i] - deg[i] + prefix;
    if (i == 0) rowptr[N] = E;
}

__global__ void fill_kernel(const int* __restrict__ ei, int E, int N,
                            const int* __restrict__ flags,
                            const int* __restrict__ rowptr, int* __restrict__ fillc,
                            int* __restrict__ csr){
    int is64 = flags[1];
    int base = blockIdx.x * 1024;
    #pragma unroll
    for (int k = 0; k < 4; k++){
        int e = base + k * 256 + threadIdx.x;
        if (e < E){
            int d = is64 ? ei[2 * E + 2 * e] : ei[E + e];
            int s = is64 ? ei[2 * e]         : ei[e];
            if ((unsigned)d < (unsigned)N){
                int p = atomicAdd(&fillc[d], 1);
                csr[rowptr[d] + p] = s;
            }
        }
    }
}

// ---------------- prep: weights -> bf16 packed chunk-major [kc][n][32], + x conversion ----------------
__global__ void prep_kernel(const void* __restrict__ W1, unsigned short* __restrict__ Wp1,
                            const void* __restrict__ W2, unsigned short* __restrict__ Wp2,
                            const void* __restrict__ W3, unsigned short* __restrict__ Wp3,
                            const void* __restrict__ x, unsigned short* __restrict__ Xc,
                            int nx8, const int* __restrict__ flags){
    int bid = blockIdx.x;
    int f32 = flags[0];
    if (bid < 640){
        const void* W; unsigned short* Wp; int base;
        if (bid < 128)      { W = W1; Wp = Wp1; base = bid; }
        else if (bid < 384) { W = W2; Wp = Wp2; base = bid - 128; }
        else                { W = W3; Wp = Wp3; base = bid - 384; }
        int idx = base * 256 + threadIdx.x;
        int k2 = idx & 31;
        int nn = (idx >> 5) & 255;
        int kc = idx >> 13;
        Wp[idx] = f2bf(ldf(W, (kc * 32 + k2) * 256 + nn, f32));
    } else {
        int i = (bid - 640) * 256 + threadIdx.x;
        if (i >= nx8) return;
        int base = i * 8;
        unsigned short o[8];
        if (f32){
            const float* s = (const float*)x + base;
            float4 a = *(const float4*)s;
            float4 b = *(const float4*)(s + 4);
            o[0]=f2bf(a.x); o[1]=f2bf(a.y); o[2]=f2bf(a.z); o[3]=f2bf(a.w);
            o[4]=f2bf(b.x); o[5]=f2bf(b.y); o[6]=f2bf(b.z); o[7]=f2bf(b.w);
        } else {
            *(uint4*)o = *(const uint4*)((const unsigned short*)x + base);
        }
        *(uint4*)&Xc[base] = *(uint4*)o;
    }
}

// ---------------- plain vectorized aggregation ----------------
template<int C>
__global__ __launch_bounds__(256) void agg_vec(const unsigned short* __restrict__ feat, int ldi,
                                               const int* __restrict__ rowptr, const int* __restrict__ csr,
                                               unsigned short* __restrict__ Y, int ldo, int N){
    constexpr int L   = C / 8;
    constexpr int NPB = 256 / L;
    int node = blockIdx.x * NPB + threadIdx.x / L;
    int lane = threadIdx.x & (L - 1);
    if (node >= N) return;
    int c0 = lane * 8;
    const unsigned short* base = feat + c0;

    U8 t0; t0.v = *(const u32x4*)&feat[(size_t)node * ldi + c0];
    float acc[8];
    #pragma unroll
    for (int j = 0; j < 8; j++) acc[j] = bf2f(t0.s[j]);

    int lo = rowptr[node], hi = rowptr[node + 1];
    int e = lo;
    for (; e + 3 < hi; e += 4){
        int s0 = csr[e], s1 = csr[e + 1], s2 = csr[e + 2], s3 = csr[e + 3];
        U8 ta, tb, tc, td;
        ta.v = *(const u32x4*)&base[(size_t)s0 * ldi];
        tb.v = *(const u32x4*)&base[(size_t)s1 * ldi];
        tc.v = *(const u32x4*)&base[(size_t)s2 * ldi];
        td.v = *(const u32x4*)&base[(size_t)s3 * ldi];
        #pragma unroll
        for (int j = 0; j < 8; j++)
            acc[j] += (bf2f(ta.s[j]) + bf2f(tb.s[j])) + (bf2f(tc.s[j]) + bf2f(td.s[j]));
    }
    for (; e < hi; e++){
        int s0 = csr[e];
        U8 ta; ta.v = *(const u32x4*)&base[(size_t)s0 * ldi];
        #pragma unroll
        for (int j = 0; j < 8; j++) acc[j] += bf2f(ta.s[j]);
    }
    U8 o;
    #pragma unroll
    for (int j = 0; j < 8; j++) o.s[j] = f2bf(acc[j]);
    *(u32x4*)&Y[(size_t)node * ldo + c0] = o.v;
}

// ---- flat GEMM, 64-row in-place blocks (grid 782), BK=32 packed-B, LDS C-staging. ----
// Round-15 config (best measured). C/D layout col=lane&15, row=(lane>>4)*4+reg [m89].
__global__ __launch_bounds__(256) void gemm_tile(
    unsigned short* __restrict__ AC, int K,
    const unsigned short* __restrict__ Bp, const void* __restrict__ bias,
    int M, const int* __restrict__ flags,
    float* __restrict__ S, float* __restrict__ Q)   // S,Q: NSH shadow copies of 256
{
    __shared__ __align__(16) unsigned short smem[64 * CSTR];  // 33.8 KB: As+Bs in K-loop, Cs in epilogue
    __shared__ float sS[256], sQ[256];
    unsigned short* As = smem;              // 64*40 = 2560 shorts
    unsigned short* Bs = smem + 2560;       // 256*40 = 10240 shorts
    const int tid  = threadIdx.x;
    const int wave = tid >> 6, lane = tid & 63;
    const int quad = lane >> 4, l16 = lane & 15;
    const int m0   = blockIdx.x * 64;
    const int wn   = wave * 64;
    const bool full = (m0 + 64 <= M);
    const int f32  = flags[0];

    const f32x4 zero4 = {0.f, 0.f, 0.f, 0.f};
    f32x4 acc[4][4];
    #pragma unroll
    for (int i = 0; i < 4; i++)
        #pragma unroll
        for (int j = 0; j < 4; j++) acc[i][j] = zero4;

    const int nchunk = K >> 5;
    for (int kc8 = 0; kc8 < nchunk; kc8++){
        int kc = kc8 * 32;
        {
            int r = tid >> 2, cc = (tid & 3) * 8;
            int gr = m0 + r;
            uint4 va; va.x = va.y = va.z = va.w = 0u;
            if (full || gr < M) va = *(const uint4*)&AC[(size_t)gr * HDIM + kc + cc];
            *(uint4*)&As[r * 40 + cc] = va;
        }
        {
            const unsigned short* bc = Bp + (size_t)kc8 * 8192;
            #pragma unroll
            for (int j = 0; j < 4; j++){
                int c = tid + j * 256;
                int n = c >> 2, seg = (c & 3) * 8;
                *(uint4*)&Bs[n * 40 + seg] = *(const uint4*)&bc[c * 8];
            }
        }
        __syncthreads();
        s16x8 af[4], bfr[4];
        #pragma unroll
        for (int mt = 0; mt < 4; mt++)
            af[mt] = *(const s16x8*)&As[(mt * 16 + l16) * 40 + quad * 8];
        #pragma unroll
        for (int nt = 0; nt < 4; nt++)
            bfr[nt] = *(const s16x8*)&Bs[(wn + nt * 16 + l16) * 40 + quad * 8];
        #pragma unroll
        for (int mt = 0; mt < 4; mt++)
            #pragma unroll
            for (int nt = 0; nt < 4; nt++)
                acc[mt][nt] = __builtin_amdgcn_mfma_f32_16x16x32_bf16(af[mt], bfr[nt], acc[mt][nt], 0, 0, 0);
        __syncthreads();
    }
    // epilogue: stage C into LDS; quad-reduce stats via shfl, single-writer LDS stores
    #pragma unroll
    for (int nt = 0; nt < 4; nt++){
        int gc = wn + nt * 16 + l16;
        float bv = ldf(bias, gc, f32);
        float ps = 0.f, pq = 0.f;
        #pragma unroll
        for (int mt = 0; mt < 4; mt++){
            #pragma unroll
            for (int r = 0; r < 4; r++){
                int lr = mt * 16 + quad * 4 + r;
                float val = acc[mt][nt][r] + bv;
                smem[lr * CSTR + gc] = f2bf(val);
                if (full || (m0 + lr) < M){ ps += val; pq += val * val; }
            }
        }
        ps += __shfl_xor(ps, 16); ps += __shfl_xor(ps, 32);
        pq += __shfl_xor(pq, 16); pq += __shfl_xor(pq, 32);
        if (quad == 0){ sS[gc] = ps; sQ[gc] = pq; }
    }
    __syncthreads();
    // coalesced full-line C stores: 32 threads cover one 512B row
    #pragma unroll
    for (int j = 0; j < 8; j++){
        int lin = j * 256 + tid;
        int row = lin >> 5, coll = (lin & 31) * 8;
        int gr = m0 + row;
        if (full || gr < M)
            *(uint4*)&AC[(size_t)gr * HDIM + coll] = *(const uint4*)&smem[row * CSTR + coll];
    }
    int sid = (blockIdx.x & (NSH - 1)) * 256 + tid;
    atomicAdd(&S[sid], sS[tid]);
    atomicAdd(&Q[sid], sQ[tid]);
}

// ---------------- bnrelu: reduce shadow stats, scale/shift, relu (+ residual); 16 elems/thread ----------------
__global__ void bnrelu_kernel(const unsigned short* __restrict__ Hin,
                              const float* __restrict__ S, const float* __restrict__ Q,
                              const void* __restrict__ g, const void* __restrict__ be,
                              float invM, const int* __restrict__ flags,
                              const unsigned short* __restrict__ res,
                              unsigned short* __restrict__ Out, int total16){
    __shared__ float sscale[256], sshift[256];
    int tid = threadIdx.x;
    {
        int f32 = flags[0];
        float s = 0.f, q = 0.f;
        #pragma unroll
        for (int k = 0; k < NSH; k++){ s += S[k * 256 + tid]; q += Q[k * 256 + tid]; }
        float m  = s * invM;
        float v  = q * invM - m * m;
        float sc = ldf(g, tid, f32) * rsqrtf(v + 1e-5f);
        sscale[tid] = sc;
        sshift[tid] = ldf(be, tid, f32) - m * sc;
    }
    __syncthreads();
    int idx = blockIdx.x * 256 + tid;
    if (idx >= total16) return;
    #pragma unroll
    for (int h = 0; h < 2; h++){
        int base = idx * 16 + h * 8;
        int c = base & (HDIM - 1);
        unsigned short hv[8], rv[8], ov[8];
        *(uint4*)hv = *(const uint4*)&Hin[base];
        if (res) *(uint4*)rv = *(const uint4*)&res[base];
        #pragma unroll
        for (int j = 0; j < 8; j++){
            float v = bf2f(hv[j]) * sscale[c + j] + sshift[c + j];
            v = (v < 0.f) ? 0.f : v;
            if (res) v += bf2f(rv[j]);
            ov[j] = f2bf(v);
        }
        *(uint4*)&Out[base] = *(uint4*)ov;
    }
}

// ---- layer-3 bnrelu + pool: 64-row strips, 8 walkers x 32 col-groups, uint4 loads. ----
__global__ __launch_bounds__(256) void bnrelu_pool_kernel(
    const unsigned short* __restrict__ H, const unsigned short* __restrict__ res,
    const float* __restrict__ S, const float* __restrict__ Q,
    const void* __restrict__ g, const void* __restrict__ be,
    float invM, const int* __restrict__ flags,
    const int* __restrict__ batch, int N, float* __restrict__ sums)
{
    __shared__ float lsc[256], lsh[256];
    __shared__ float red[8 * 256];
    int tid = threadIdx.x;
    {
        int f32 = flags[0];
        float s = 0.f, q = 0.f;
        #pragma unroll
        for (int k = 0; k < NSH; k++){ s += S[k * 256 + tid]; q += Q[k * 256 + tid]; }
        float m  = s * invM;
        float v  = q * invM - m * m;
        float sc = ldf(g, tid, f32) * rsqrtf(v + 1e-5f);
        lsc[tid] = sc;
        lsh[tid] = ldf(be, tid, f32) - m * sc;
    }
    __syncthreads();
    int r0 = blockIdx.x * 64;
    if (r0 >= N) return;
    int r1 = min(r0 + 64, N);
    int stride = flags[2] ? 2 : 1;
    int gfirst = batch[r0 * stride];
    int glast  = batch[(r1 - 1) * stride];
    int w  = tid >> 5;
    int c0 = (tid & 31) * 8;
    float sc[8], sh[8];
    #pragma unroll
    for (int j = 0; j < 8; j++){ sc[j] = lsc[c0 + j]; sh[j] = lsh[c0 + j]; }

    float acc[8];
    #pragma unroll
    for (int j = 0; j < 8; j++) acc[j] = 0.f;

    if (gfirst == glast){
        for (int r = r0 + w; r < r1; r += 8){
            U8 hv, rv;
            hv.v = *(const u32x4*)&H[(size_t)r * HDIM + c0];
            rv.v = *(const u32x4*)&res[(size_t)r * HDIM + c0];
            #pragma unroll
            for (int j = 0; j < 8; j++){
                float v = bf2f(hv.s[j]) * sc[j] + sh[j];
                v = (v < 0.f) ? 0.f : v;
                acc[j] += v + bf2f(rv.s[j]);
            }
        }
        *(float4*)&red[w * 256 + c0]     = make_float4(acc[0], acc[1], acc[2], acc[3]);
        *(float4*)&red[w * 256 + c0 + 4] = make_float4(acc[4], acc[5], acc[6], acc[7]);
        __syncthreads();
        float tot = 0.f;
        #pragma unroll
        for (int k = 0; k < 8; k++) tot += red[k * 256 + tid];
        atomicAdd(&sums[gfirst * HDIM + tid], tot);
    } else {
        int curg = batch[min(r0 + w, r1 - 1) * stride];
        for (int r = r0 + w; r < r1; r += 8){
            int gg = batch[r * stride];
            if (gg != curg){
                #pragma unroll
                for (int j = 0; j < 8; j++){
                    if (acc[j] != 0.f) atomicAdd(&sums[curg * HDIM + c0 + j], acc[j]);
                    acc[j] = 0.f;
                }
                curg = gg;
            }
            U8 hv, rv;
            hv.v = *(const u32x4*)&H[(size_t)r * HDIM + c0];
            rv.v = *(const u32x4*)&res[(size_t)r * HDIM + c0];
            #pragma unroll
            for (int j = 0; j < 8; j++){
                float v = bf2f(hv.s[j]) * sc[j] + sh[j];
                v = (v < 0.f) ? 0.f : v;
                acc[j] += v + bf2f(rv.s[j]);
            }
        }
        #pragma unroll
        for (int j = 0; j < 8; j++)
            if (acc[j] != 0.f) atomicAdd(&sums[curg * HDIM + c0 + j], acc[j]);
    }
}

// ---------------- FC head (fused pool finalize) ----------------
__global__ __launch_bounds__(256) void head_kernel(const float* __restrict__ sums,
                                                   const int* __restrict__ batch, int N,
                                                   const void* __restrict__ fcW1,
                                                   const void* __restrict__ fcb1,
                                                   const void* __restrict__ fcW2,
                                                   const void* __restrict__ fcb2,
                                                   void* __restrict__ out,
                                                   const int* __restrict__ flags){
    __shared__ float sp[256];
    __shared__ float red[256];
    __shared__ int scnt;
    int g = blockIdx.x, j = threadIdx.x;
    int f32 = flags[0];
    int stride = flags[2] ? 2 : 1;
    if (j == 0){
        int lo = 0, hi = N;
        while (lo < hi){ int mid = (lo + hi) >> 1; if (batch[mid * stride] < g) lo = mid + 1; else hi = mid; }
        int a = lo;
        lo = 0; hi = N;
        while (lo < hi){ int mid = (lo + hi) >> 1; if (batch[mid * stride] < g + 1) lo = mid + 1; else hi = mid; }
        scnt = lo - a;
    }
    __syncthreads();
    sp[j] = sums[g * HDIM + j] / (float)max(scnt, 1);
    __syncthreads();
    float acc = ldf(fcb1, j, f32);
    for (int k = 0; k < HDIM; k++) acc += sp[k] * ldf(fcW1, k * HDIM + j, f32);
    acc = (acc < 0.f) ? 0.f : acc;
    red[j] = acc * ldf(fcW2, j, f32);
    __syncthreads();
    for (int s = 128; s > 0; s >>= 1){
        if (j < s) red[j] += red[j + s];
        __syncthreads();
    }
    if (j == 0){
        float r = red[0] + ldf(fcb2, 0, f32);
        if (f32) ((float*)out)[g] = r;
        else     ((unsigned short*)out)[g] = f2bf(r);
    }
}

extern "C" void kernel_launch(void* const* d_in, const int* in_sizes, int n_in,
                              void* d_out, int out_size, void* d_ws, size_t ws_size,
                              hipStream_t stream)
{
    const unsigned short* x    = (const unsigned short*)d_in[0];
    const int*            ei   = (const int*)d_in[1];
    const int*            batch= (const int*)d_in[2];
    const void* W1   = d_in[4];
    const void* b1   = d_in[5];
    const void* W2   = d_in[6];
    const void* b2   = d_in[7];
    const void* W3   = d_in[8];
    const void* b3   = d_in[9];
    const void* g1   = d_in[10];
    const void* be1  = d_in[11];
    const void* g2   = d_in[12];
    const void* be2  = d_in[13];
    const void* g3   = d_in[14];
    const void* be3  = d_in[15];
    const void* fcW1 = d_in[16];
    const void* fcb1 = d_in[17];
    const void* fcW2 = d_in[18];
    const void* fcb2 = d_in[19];

    const int N = in_sizes[0] / 128;   // 50000
    const int E = in_sizes[1] / 2;     // 800000
    const int D = 128;

    // ---- workspace layout ----
    char* p = (char*)d_ws;
    int*   deg     = (int*)p;   p += (size_t)N * 4;
    int*   fillc   = (int*)p;   p += (size_t)N * 4;
    float* stats   = (float*)p; p += 6 * NSH * 256 * 4;
    float* poolsum = (float*)p; p += NGRAPH * HDIM * 4;
    size_t zbytes  = (size_t)(p - (char*)d_ws);
    int*   flags   = (int*)p;   p += 16 * 4;
    int*   bsums   = (int*)p;   p += 256 * 4;
    int*   rowptr  = (int*)p;   p += ((size_t)N + 4) * 4;
    int*   csr     = (int*)p;   p += (size_t)E * 4;
    unsigned short* Wp1 = (unsigned short*)p; p += 256 * 128 * 2;
    unsigned short* Wp2 = (unsigned short*)p; p += 256 * 256 * 2;
    unsigned short* Wp3 = (unsigned short*)p; p += 256 * 256 * 2;
    unsigned short* B1  = (unsigned short*)p; p += (size_t)N * HDIM * 2;
    unsigned short* B2  = (unsigned short*)p; p += (size_t)N * HDIM * 2;
    unsigned short* Xc  = B1;   // Xc dead before B1 born

    float* S0 = stats + 0 * NSH * 256; float* Q0 = stats + 1 * NSH * 256;
    float* S1 = stats + 2 * NSH * 256; float* Q1 = stats + 3 * NSH * 256;
    float* S2 = stats + 4 * NSH * 256; float* Q2 = stats + 5 * NSH * 256;

    const int nbN = (N + 255) / 256;       // 196
    const int nbE4 = (E + 1023) / 1024;    // 782
    const int gM64  = (N + 63) / 64;       // 782
    const float invM = 1.0f / (float)N;
    const int total16 = N * HDIM / 16;
    const int zn = (int)(zbytes / 4);
    const int nx8 = N * D / 8;             // 800000

    zero_detect_kernel<<<(zn + 255) / 256, 256, 0, stream>>>((int*)d_ws, zn, x, ei, batch, E, N, flags);

    // CSR build
    hist_kernel<<<nbE4, 256, 0, stream>>>(ei, E, N, flags, deg);
    scan1_kernel<<<nbN, 256, 0, stream>>>(deg, N, rowptr, bsums);
    scan23_kernel<<<nbN, 256, 0, stream>>>(deg, N, E, nbN, bsums, rowptr);
    fill_kernel<<<nbE4, 256, 0, stream>>>(ei, E, N, flags, rowptr, fillc, csr);

    // weights (packed) + x conversion
    prep_kernel<<<640 + (nx8 + 255) / 256, 256, 0, stream>>>(W1, Wp1, W2, Wp2, W3, Wp3, x, Xc, nx8, flags);

    // ---- Layer 1 ----
    agg_vec<128><<<(N + 15) / 16, 256, 0, stream>>>(Xc, D, rowptr, csr, B2, HDIM, N);
    gemm_tile<<<gM64, 256, 0, stream>>>(B2, 128, Wp1, b1, N, flags, S0, Q0);
    bnrelu_kernel<<<(total16 + 255) / 256, 256, 0, stream>>>(
        B2, S0, Q0, g1, be1, invM, flags, (const unsigned short*)nullptr, B1, total16);

    // ---- Layer 2 ----
    agg_vec<256><<<(N + 7) / 8, 256, 0, stream>>>(B1, HDIM, rowptr, csr, B2, HDIM, N);
    gemm_tile<<<gM64, 256, 0, stream>>>(B2, 256, Wp2, b2, N, flags, S1, Q1);
    bnrelu_kernel<<<(total16 + 255) / 256, 256, 0, stream>>>(
        B2, S1, Q1, g2, be2, invM, flags, B1, B1, total16);

    // ---- Layer 3 (bnrelu fused with pooling) ----
    agg_vec<256><<<(N + 7) / 8, 256, 0, stream>>>(B1, HDIM, rowptr, csr, B2, HDIM, N);
    gemm_tile<<<gM64, 256, 0, stream>>>(B2, 256, Wp3, b3, N, flags, S2, Q2);
    bnrelu_pool_kernel<<<gM64, 256, 0, stream>>>(
        B2, B1, S2, Q2, g3, be3, invM, flags, batch, N, poolsum);

    // ---- Head ----
    head_kernel<<<NGRAPH, 256, 0, stream>>>(poolsum, batch, N, fcW1, fcb1, fcW2, fcb2, d_out, flags);

    (void)n_in; (void)out_size; (void)ws_size;
}